// Round 1
// baseline (395.609 us; speedup 1.0000x reference)
//
#include <hip/hip_runtime.h>
#include <cstdint>
#include <cstddef>

#define NTOK 8192
#define D    1024
#define DFF  4096
#define NEXP 8
#define CAP  1126
#define MPAD 1152   // 9*128, padded per-expert rows

typedef float f32x4 __attribute__((ext_vector_type(4)));
typedef __bf16 bf16x8 __attribute__((ext_vector_type(8)));

__device__ inline unsigned short f2bf(float f) {
    unsigned u = __float_as_uint(f);
    u += 0x7fffu + ((u >> 16) & 1u);   // round-to-nearest-even
    return (unsigned short)(u >> 16);
}

__device__ inline void gload16(const void* g, void* l) {
    __builtin_amdgcn_global_load_lds(
        (const __attribute__((address_space(1))) unsigned int*)g,
        (__attribute__((address_space(3))) unsigned int*)l,
        16, 0, 0);
}

// ---------------- router: logits argmax, one wave per token ----------------
__global__ __launch_bounds__(256) void router_kernel(
    const float* __restrict__ x, const float* __restrict__ gw, int* __restrict__ eidx)
{
    int tok  = blockIdx.x * 4 + (threadIdx.x >> 6);
    int lane = threadIdx.x & 63;
    const float* xr = x + (size_t)tok * D;
    float a[8] = {0.f,0.f,0.f,0.f,0.f,0.f,0.f,0.f};
    #pragma unroll
    for (int it = 0; it < D / 64; ++it) {
        int d = lane + it * 64;
        float xv = xr[d];
        const float4 g0 = *(const float4*)(gw + (size_t)d * 8);
        const float4 g1 = *(const float4*)(gw + (size_t)d * 8 + 4);
        a[0] += xv * g0.x; a[1] += xv * g0.y; a[2] += xv * g0.z; a[3] += xv * g0.w;
        a[4] += xv * g1.x; a[5] += xv * g1.y; a[6] += xv * g1.z; a[7] += xv * g1.w;
    }
    #pragma unroll
    for (int off = 32; off > 0; off >>= 1)
        #pragma unroll
        for (int e = 0; e < 8; ++e) a[e] += __shfl_xor(a[e], off, 64);
    if (lane == 0) {
        int bi = 0; float bv = a[0];
        #pragma unroll
        for (int e = 1; e < 8; ++e) if (a[e] > bv) { bv = a[e]; bi = e; }
        eidx[tok] = bi;
    }
}

// ------------- scan: cumulative per-expert positions, slot map, loss -------------
__global__ __launch_bounds__(1024) void scan_kernel(
    const int* __restrict__ eidx, int* __restrict__ slot_map,
    int* __restrict__ kept_cnt, float* __restrict__ loss_out)
{
    __shared__ int sc[8][1024];
    int t = threadIdx.x;
    int le[8];
    int c[8] = {0,0,0,0,0,0,0,0};
    #pragma unroll
    for (int i = 0; i < 8; ++i) { le[i] = eidx[t * 8 + i]; c[le[i]]++; }
    int v[8];
    #pragma unroll
    for (int e = 0; e < 8; ++e) { v[e] = c[e]; sc[e][t] = v[e]; }
    __syncthreads();
    for (int s = 1; s < 1024; s <<= 1) {
        int add[8] = {0,0,0,0,0,0,0,0};
        if (t >= s) {
            #pragma unroll
            for (int e = 0; e < 8; ++e) add[e] = sc[e][t - s];
        }
        __syncthreads();
        #pragma unroll
        for (int e = 0; e < 8; ++e) { v[e] += add[e]; sc[e][t] = v[e]; }
        __syncthreads();
    }
    int base[8];
    #pragma unroll
    for (int e = 0; e < 8; ++e) base[e] = v[e] - c[e];
    #pragma unroll
    for (int i = 0; i < 8; ++i) {
        int e = le[i]; int pos = base[e]++;
        if (pos < CAP) slot_map[e * CAP + pos] = t * 8 + i;
    }
    if (t == 1023) {
        float dotv = 0.f, ss = 0.f;
        #pragma unroll
        for (int e = 0; e < 8; ++e) {
            float cf = (float)v[e];
            kept_cnt[e] = v[e] < CAP ? v[e] : CAP;
            dotv += cf * 1024.0f;
            ss   += cf * cf;
        }
        float denom = sqrtf(ss) * (1024.0f * sqrtf(8.0f)) + 1e-8f;
        loss_out[0] = 1.0f - 0.01f * (dotv / denom);
    }
}

// ---------------- zero-fill output tokens ----------------
__global__ __launch_bounds__(256) void zero_out(float4* __restrict__ p, int n)
{
    int stride = gridDim.x * blockDim.x;
    for (int i = blockIdx.x * blockDim.x + threadIdx.x; i < n; i += stride)
        p[i] = make_float4(0.f, 0.f, 0.f, 0.f);
}

// ---------------- dispatch + LayerNorm -> bf16 xbuf [E][MPAD][D] ----------------
__global__ __launch_bounds__(256) void dispatch_ln(
    const float* __restrict__ x, const float* __restrict__ lng, const float* __restrict__ lnb,
    const int* __restrict__ slot_map, const int* __restrict__ kept_cnt,
    unsigned short* __restrict__ xbuf)
{
    int p = blockIdx.x, e = blockIdx.y, tid = threadIdx.x;
    ushort4* dst = (ushort4*)(xbuf + ((size_t)e * MPAD + p) * D) + tid;
    if (p >= kept_cnt[e]) { *dst = make_ushort4(0, 0, 0, 0); return; }
    int tok = slot_map[e * CAP + p];
    const float4 xv = *((const float4*)(x + (size_t)tok * D) + tid);
    float s  = xv.x + xv.y + xv.z + xv.w;
    float ss = xv.x * xv.x + xv.y * xv.y + xv.z * xv.z + xv.w * xv.w;
    #pragma unroll
    for (int off = 32; off > 0; off >>= 1) {
        s  += __shfl_xor(s,  off, 64);
        ss += __shfl_xor(ss, off, 64);
    }
    __shared__ float red[8];
    int lane = tid & 63, wv = tid >> 6;
    if (lane == 0) { red[wv] = s; red[4 + wv] = ss; }
    __syncthreads();
    s  = red[0] + red[1] + red[2] + red[3];
    ss = red[4] + red[5] + red[6] + red[7];
    float mu = s * (1.0f / D);
    float rs = rsqrtf(ss * (1.0f / D) - mu * mu + 1e-5f);
    const float4 gv = *((const float4*)(lng + (size_t)e * D) + tid);
    const float4 bv = *((const float4*)(lnb + (size_t)e * D) + tid);
    ushort4 o;
    o.x = f2bf((xv.x - mu) * rs * gv.x + bv.x);
    o.y = f2bf((xv.y - mu) * rs * gv.y + bv.y);
    o.z = f2bf((xv.z - mu) * rs * gv.z + bv.z);
    o.w = f2bf((xv.w - mu) * rs * gv.w + bv.w);
    *dst = o;
}

// ---------------- transpose + fp32->bf16: W[E][K][N] -> WT[E][N][K] ----------------
__global__ __launch_bounds__(256) void transpose_bf16(
    const float* __restrict__ W, unsigned short* __restrict__ WT, int K, int N)
{
    __shared__ float t[64][65];
    int e = blockIdx.z;
    int n0 = blockIdx.x * 64, k0 = blockIdx.y * 64;
    const float* We = W + (size_t)e * K * N;
    unsigned short* WTe = WT + (size_t)e * K * N;
    int tx = threadIdx.x & 15, ty = threadIdx.x >> 4;
    #pragma unroll
    for (int j = 0; j < 4; ++j) {
        int k = ty + 16 * j;
        const float4 v = *(const float4*)(We + (size_t)(k0 + k) * N + n0 + tx * 4);
        t[k][tx * 4 + 0] = v.x; t[k][tx * 4 + 1] = v.y;
        t[k][tx * 4 + 2] = v.z; t[k][tx * 4 + 3] = v.w;
    }
    __syncthreads();
    #pragma unroll
    for (int j = 0; j < 4; ++j) {
        int n = ty + 16 * j;
        ushort4 o;
        o.x = f2bf(t[tx * 4 + 0][n]); o.y = f2bf(t[tx * 4 + 1][n]);
        o.z = f2bf(t[tx * 4 + 2][n]); o.w = f2bf(t[tx * 4 + 3][n]);
        *(ushort4*)(WTe + (size_t)(n0 + n) * K + k0 + tx * 4) = o;
    }
}

// ---------------- GEMM: C[E][MPAD][N] = A[E][MPAD][K] @ BT[E][N][K]^T + bias ----------------
// MODE 0: epilogue = exact GELU, store bf16 to Hout
// MODE 1: epilogue = scatter fp32 rows (< kept) to Yout via slot_map
template<int K, int N, int MODE>
__global__ __launch_bounds__(256, 2) void gemm_kernel(
    const unsigned short* __restrict__ A,
    const unsigned short* __restrict__ BT,
    const float* __restrict__ bias,
    unsigned short* __restrict__ Hout,
    float* __restrict__ Yout,
    const int* __restrict__ slot_map,
    const int* __restrict__ kept_cnt)
{
    const int nb = blockIdx.x, mb = blockIdx.y, e = blockIdx.z;
    const int tid  = threadIdx.x;
    const int lane = tid & 63;
    const int l15  = lane & 15, lg = lane >> 4;
    const int wave = tid >> 6, wr = wave >> 1, wc = wave & 1;
    __shared__ __align__(16) char smem[16384];   // A tile 8KB | B tile 8KB
    const unsigned short* Ae = A + ((size_t)e * MPAD + (size_t)mb * 128) * K;
    const unsigned short* Be = BT + ((size_t)e * N + (size_t)nb * 128) * K;
    f32x4 acc[4][4] = {};

    for (int kk = 0; kk < K / 32; ++kk) {
        __syncthreads();
        #pragma unroll
        for (int q = 0; q < 2; ++q) {
            int cid = q * 256 + tid;          // 0..511 chunk of 16B
            int row = cid >> 2, pp = cid & 3;
            int cc  = pp ^ ((row >> 1) & 3);  // source chunk for swizzled LDS pos
            gload16(Ae + (size_t)row * K + kk * 32 + cc * 8, smem + cid * 16);
            gload16(Be + (size_t)row * K + kk * 32 + cc * 8, smem + 8192 + cid * 16);
        }
        __syncthreads();
        bf16x8 af[4], bfr[4];
        #pragma unroll
        for (int i = 0; i < 4; ++i) {
            int ra = wr * 64 + i * 16 + l15;
            af[i]  = *(const bf16x8*)(smem + ra * 64 + ((lg ^ ((ra >> 1) & 3)) << 4));
            int rb = wc * 64 + i * 16 + l15;
            bfr[i] = *(const bf16x8*)(smem + 8192 + rb * 64 + ((lg ^ ((rb >> 1) & 3)) << 4));
        }
        #pragma unroll
        for (int mi = 0; mi < 4; ++mi)
            #pragma unroll
            for (int ni = 0; ni < 4; ++ni)
                acc[mi][ni] = __builtin_amdgcn_mfma_f32_16x16x32_bf16(
                    af[mi], bfr[ni], acc[mi][ni], 0, 0, 0);
    }

    const int kept = (MODE == 1) ? kept_cnt[e] : 0;
    #pragma unroll
    for (int mi = 0; mi < 4; ++mi) {
        #pragma unroll
        for (int ni = 0; ni < 4; ++ni) {
            int col = nb * 128 + wc * 64 + ni * 16 + l15;
            float bv = bias[(size_t)e * N + col];
            #pragma unroll
            for (int j = 0; j < 4; ++j) {
                int row = mb * 128 + wr * 64 + mi * 16 + 4 * lg + j;
                float v = acc[mi][ni][j] + bv;
                if (MODE == 0) {
                    v = 0.5f * v * (1.0f + erff(v * 0.70710678118654752f));
                    Hout[((size_t)e * MPAD + row) * N + col] = f2bf(v);
                } else {
                    if (row < kept) {
                        int tok = slot_map[e * CAP + row];
                        Yout[(size_t)tok * D + col] = v;
                    }
                }
            }
        }
    }
}

extern "C" void kernel_launch(void* const* d_in, const int* in_sizes, int n_in,
                              void* d_out, int out_size, void* d_ws, size_t ws_size,
                              hipStream_t stream)
{
    const float* x   = (const float*)d_in[0];
    const float* gw  = (const float*)d_in[1];
    const float* lng = (const float*)d_in[2];
    const float* lnb = (const float*)d_in[3];
    const float* w1  = (const float*)d_in[4];
    const float* b1  = (const float*)d_in[5];
    const float* w2  = (const float*)d_in[6];
    const float* b2  = (const float*)d_in[7];
    float* out = (float*)d_out;

    char* ws = (char*)d_ws;
    unsigned short* wT   = (unsigned short*)ws;                               // 67108864 B (reused for w1T then w2T)
    unsigned short* xbuf = (unsigned short*)(ws + 67108864);                  // 18874368 B
    unsigned short* hbuf = (unsigned short*)(ws + 67108864 + 18874368);       // 75497472 B
    int* eidx     = (int*)(ws + 161480704);
    int* slot_map = eidx + NTOK;
    int* kept     = slot_map + NEXP * CAP;

    router_kernel<<<NTOK / 4, 256, 0, stream>>>(x, gw, eidx);
    scan_kernel<<<1, 1024, 0, stream>>>(eidx, slot_map, kept, out + (size_t)NTOK * D);
    zero_out<<<2048, 256, 0, stream>>>((float4*)out, NTOK * D / 4);
    dispatch_ln<<<dim3(MPAD, NEXP), 256, 0, stream>>>(x, lng, lnb, slot_map, kept, xbuf);

    // GEMM1: h = gelu(xbuf @ w1 + b1)
    transpose_bf16<<<dim3(DFF / 64, D / 64, NEXP), 256, 0, stream>>>(w1, wT, D, DFF);
    gemm_kernel<D, DFF, 0><<<dim3(DFF / 128, MPAD / 128, NEXP), 256, 0, stream>>>(
        xbuf, wT, b1, hbuf, nullptr, slot_map, kept);

    // GEMM2: out[token] = h @ w2 + b2 (scatter)
    transpose_bf16<<<dim3(D / 64, DFF / 64, NEXP), 256, 0, stream>>>(w2, wT, DFF, D);
    gemm_kernel<DFF, D, 1><<<dim3(D / 128, MPAD / 128, NEXP), 256, 0, stream>>>(
        hbuf, wT, b2, nullptr, out, slot_map, kept);
}

// Round 2
// 336.112 us; speedup vs baseline: 1.1770x; 1.1770x over previous
//
#include <hip/hip_runtime.h>
#include <cstdint>
#include <cstddef>

#define NTOK 8192
#define D    1024
#define DFF  4096
#define NEXP 8
#define CAP  1126
#define MPAD 1152   // 9*128, padded per-expert rows

typedef float f32x4 __attribute__((ext_vector_type(4)));
typedef __bf16 bf16x8 __attribute__((ext_vector_type(8)));

__device__ inline unsigned short f2bf(float f) {
    unsigned u = __float_as_uint(f);
    u += 0x7fffu + ((u >> 16) & 1u);   // round-to-nearest-even
    return (unsigned short)(u >> 16);
}

__device__ inline void gload16(const void* g, void* l) {
    __builtin_amdgcn_global_load_lds(
        (const __attribute__((address_space(1))) unsigned int*)g,
        (__attribute__((address_space(3))) unsigned int*)l,
        16, 0, 0);
}

// ---------------- router: logits argmax, one wave per token ----------------
__global__ __launch_bounds__(256) void router_kernel(
    const float* __restrict__ x, const float* __restrict__ gw, int* __restrict__ eidx)
{
    int tok  = blockIdx.x * 4 + (threadIdx.x >> 6);
    int lane = threadIdx.x & 63;
    const float* xr = x + (size_t)tok * D;
    float a[8] = {0.f,0.f,0.f,0.f,0.f,0.f,0.f,0.f};
    #pragma unroll
    for (int it = 0; it < D / 64; ++it) {
        int d = lane + it * 64;
        float xv = xr[d];
        const float4 g0 = *(const float4*)(gw + (size_t)d * 8);
        const float4 g1 = *(const float4*)(gw + (size_t)d * 8 + 4);
        a[0] += xv * g0.x; a[1] += xv * g0.y; a[2] += xv * g0.z; a[3] += xv * g0.w;
        a[4] += xv * g1.x; a[5] += xv * g1.y; a[6] += xv * g1.z; a[7] += xv * g1.w;
    }
    #pragma unroll
    for (int off = 32; off > 0; off >>= 1)
        #pragma unroll
        for (int e = 0; e < 8; ++e) a[e] += __shfl_xor(a[e], off, 64);
    if (lane == 0) {
        int bi = 0; float bv = a[0];
        #pragma unroll
        for (int e = 1; e < 8; ++e) if (a[e] > bv) { bv = a[e]; bi = e; }
        eidx[tok] = bi;
    }
}

// ------------- scan: cumulative per-expert positions, slot map, loss -------------
__global__ __launch_bounds__(1024) void scan_kernel(
    const int* __restrict__ eidx, int* __restrict__ slot_map,
    int* __restrict__ kept_cnt, float* __restrict__ loss_out)
{
    __shared__ int sc[8][1024];
    int t = threadIdx.x;
    int le[8];
    int c[8] = {0,0,0,0,0,0,0,0};
    #pragma unroll
    for (int i = 0; i < 8; ++i) { le[i] = eidx[t * 8 + i]; c[le[i]]++; }
    int v[8];
    #pragma unroll
    for (int e = 0; e < 8; ++e) { v[e] = c[e]; sc[e][t] = v[e]; }
    __syncthreads();
    for (int s = 1; s < 1024; s <<= 1) {
        int add[8] = {0,0,0,0,0,0,0,0};
        if (t >= s) {
            #pragma unroll
            for (int e = 0; e < 8; ++e) add[e] = sc[e][t - s];
        }
        __syncthreads();
        #pragma unroll
        for (int e = 0; e < 8; ++e) { v[e] += add[e]; sc[e][t] = v[e]; }
        __syncthreads();
    }
    int base[8];
    #pragma unroll
    for (int e = 0; e < 8; ++e) base[e] = v[e] - c[e];
    #pragma unroll
    for (int i = 0; i < 8; ++i) {
        int e = le[i]; int pos = base[e]++;
        if (pos < CAP) slot_map[e * CAP + pos] = t * 8 + i;
    }
    if (t == 1023) {
        float dotv = 0.f, ss = 0.f;
        #pragma unroll
        for (int e = 0; e < 8; ++e) {
            float cf = (float)v[e];
            kept_cnt[e] = v[e] < CAP ? v[e] : CAP;
            dotv += cf * 1024.0f;
            ss   += cf * cf;
        }
        float denom = sqrtf(ss) * (1024.0f * sqrtf(8.0f)) + 1e-8f;
        loss_out[0] = 1.0f - 0.01f * (dotv / denom);
    }
}

// ---------------- zero-fill output tokens ----------------
__global__ __launch_bounds__(256) void zero_out(float4* __restrict__ p, int n)
{
    int stride = gridDim.x * blockDim.x;
    for (int i = blockIdx.x * blockDim.x + threadIdx.x; i < n; i += stride)
        p[i] = make_float4(0.f, 0.f, 0.f, 0.f);
}

// ---------------- dispatch + LayerNorm -> bf16 xbuf [E][MPAD][D] ----------------
__global__ __launch_bounds__(256) void dispatch_ln(
    const float* __restrict__ x, const float* __restrict__ lng, const float* __restrict__ lnb,
    const int* __restrict__ slot_map, const int* __restrict__ kept_cnt,
    unsigned short* __restrict__ xbuf)
{
    int p = blockIdx.x, e = blockIdx.y, tid = threadIdx.x;
    ushort4* dst = (ushort4*)(xbuf + ((size_t)e * MPAD + p) * D) + tid;
    if (p >= kept_cnt[e]) { *dst = make_ushort4(0, 0, 0, 0); return; }
    int tok = slot_map[e * CAP + p];
    const float4 xv = *((const float4*)(x + (size_t)tok * D) + tid);
    float s  = xv.x + xv.y + xv.z + xv.w;
    float ss = xv.x * xv.x + xv.y * xv.y + xv.z * xv.z + xv.w * xv.w;
    #pragma unroll
    for (int off = 32; off > 0; off >>= 1) {
        s  += __shfl_xor(s,  off, 64);
        ss += __shfl_xor(ss, off, 64);
    }
    __shared__ float red[8];
    int lane = tid & 63, wv = tid >> 6;
    if (lane == 0) { red[wv] = s; red[4 + wv] = ss; }
    __syncthreads();
    s  = red[0] + red[1] + red[2] + red[3];
    ss = red[4] + red[5] + red[6] + red[7];
    float mu = s * (1.0f / D);
    float rs = rsqrtf(ss * (1.0f / D) - mu * mu + 1e-5f);
    const float4 gv = *((const float4*)(lng + (size_t)e * D) + tid);
    const float4 bv = *((const float4*)(lnb + (size_t)e * D) + tid);
    ushort4 o;
    o.x = f2bf((xv.x - mu) * rs * gv.x + bv.x);
    o.y = f2bf((xv.y - mu) * rs * gv.y + bv.y);
    o.z = f2bf((xv.z - mu) * rs * gv.z + bv.z);
    o.w = f2bf((xv.w - mu) * rs * gv.w + bv.w);
    *dst = o;
}

// ---------------- transpose + fp32->bf16: W[E][K][N] -> WT[E][N][K] ----------------
__global__ __launch_bounds__(256) void transpose_bf16(
    const float* __restrict__ W, unsigned short* __restrict__ WT, int K, int N)
{
    __shared__ float t[64][65];
    int e = blockIdx.z;
    int n0 = blockIdx.x * 64, k0 = blockIdx.y * 64;
    const float* We = W + (size_t)e * K * N;
    unsigned short* WTe = WT + (size_t)e * K * N;
    int tx = threadIdx.x & 15, ty = threadIdx.x >> 4;
    #pragma unroll
    for (int j = 0; j < 4; ++j) {
        int k = ty + 16 * j;
        const float4 v = *(const float4*)(We + (size_t)(k0 + k) * N + n0 + tx * 4);
        t[k][tx * 4 + 0] = v.x; t[k][tx * 4 + 1] = v.y;
        t[k][tx * 4 + 2] = v.z; t[k][tx * 4 + 3] = v.w;
    }
    __syncthreads();
    #pragma unroll
    for (int j = 0; j < 4; ++j) {
        int n = ty + 16 * j;
        ushort4 o;
        o.x = f2bf(t[tx * 4 + 0][n]); o.y = f2bf(t[tx * 4 + 1][n]);
        o.z = f2bf(t[tx * 4 + 2][n]); o.w = f2bf(t[tx * 4 + 3][n]);
        *(ushort4*)(WTe + (size_t)(n0 + n) * K + k0 + tx * 4) = o;
    }
}

// ---------------- GEMM: C[E][MPAD][N] = A[E][MPAD][K] @ BT[E][N][K]^T + bias ----------------
// 2-phase double-buffered LDS + bijective XCD swizzle (mb-fastest for L2 B/A reuse).
// MODE 0: epilogue = exact GELU, store bf16 to Hout
// MODE 1: epilogue = scatter fp32 rows (< kept) to Yout via slot_map
template<int K, int N, int MODE>
__global__ __launch_bounds__(256, 2) void gemm_kernel(
    const unsigned short* __restrict__ A,
    const unsigned short* __restrict__ BT,
    const float* __restrict__ bias,
    unsigned short* __restrict__ Hout,
    float* __restrict__ Yout,
    const int* __restrict__ slot_map,
    const int* __restrict__ kept_cnt)
{
    constexpr int MB = MPAD / 128;
    constexpr int NB = N / 128;
    // bijective XCD chunking (m204), then decompose with mb FASTEST so the 9
    // consecutive blocks on one XCD share a single B panel (L2-resident).
    const int T = NEXP * MB * NB;
    const int orig = blockIdx.x;
    const int q8 = T >> 3, r8 = T & 7;
    const int xcd = orig & 7, ii = orig >> 3;
    const int swz = (xcd < r8 ? xcd * (q8 + 1) : r8 * (q8 + 1) + (xcd - r8) * q8) + ii;
    const int mb = swz % MB;
    const int t2 = swz / MB;
    const int nb = t2 % NB;
    const int e  = t2 / NB;

    const int tid  = threadIdx.x;
    const int lane = tid & 63;
    const int l15  = lane & 15, lg = lane >> 4;
    const int wave = tid >> 6, wr = wave >> 1, wc = wave & 1;
    __shared__ __align__(16) char smem[32768];   // 2 x (A 8KB | B 8KB)
    const unsigned short* Ae = A + ((size_t)e * MPAD + (size_t)mb * 128) * K;
    const unsigned short* Be = BT + ((size_t)e * N + (size_t)nb * 128) * K;
    f32x4 acc[4][4] = {};

    auto stage = [&](int buf, int kk) {
        char* sA = smem + buf * 16384;
        char* sB = sA + 8192;
        #pragma unroll
        for (int q = 0; q < 2; ++q) {
            int cid = q * 256 + tid;          // 0..511 chunk of 16B
            int row = cid >> 2, pp = cid & 3;
            int cc  = pp ^ ((row >> 1) & 3);  // source chunk for swizzled LDS pos
            gload16(Ae + (size_t)row * K + kk * 32 + cc * 8, sA + cid * 16);
            gload16(Be + (size_t)row * K + kk * 32 + cc * 8, sB + cid * 16);
        }
    };
    auto compute = [&](int buf) {
        const char* sA = smem + buf * 16384;
        const char* sB = sA + 8192;
        bf16x8 af[4], bfr[4];
        #pragma unroll
        for (int i = 0; i < 4; ++i) {
            int ra = wr * 64 + i * 16 + l15;
            af[i]  = *(const bf16x8*)(sA + ra * 64 + ((lg ^ ((ra >> 1) & 3)) << 4));
            int rb = wc * 64 + i * 16 + l15;
            bfr[i] = *(const bf16x8*)(sB + rb * 64 + ((lg ^ ((rb >> 1) & 3)) << 4));
        }
        #pragma unroll
        for (int mi = 0; mi < 4; ++mi)
            #pragma unroll
            for (int ni = 0; ni < 4; ++ni)
                acc[mi][ni] = __builtin_amdgcn_mfma_f32_16x16x32_bf16(
                    af[mi], bfr[ni], acc[mi][ni], 0, 0, 0);
    };

    // prologue
    stage(0, 0);
    asm volatile("s_waitcnt vmcnt(0)" ::: "memory");
    __syncthreads();
    int cur = 0;
    for (int kk = 0; kk + 1 < K / 32; ++kk) {
        stage(cur ^ 1, kk + 1);    // issue next tile while computing current
        compute(cur);
        asm volatile("s_waitcnt vmcnt(0)" ::: "memory");
        __syncthreads();
        cur ^= 1;
    }
    compute(cur);                  // last tile, no prefetch

    const int kept = (MODE == 1) ? kept_cnt[e] : 0;
    #pragma unroll
    for (int mi = 0; mi < 4; ++mi) {
        #pragma unroll
        for (int ni = 0; ni < 4; ++ni) {
            int col = nb * 128 + wc * 64 + ni * 16 + l15;
            float bv = bias[(size_t)e * N + col];
            #pragma unroll
            for (int j = 0; j < 4; ++j) {
                int row = mb * 128 + wr * 64 + mi * 16 + 4 * lg + j;
                float v = acc[mi][ni][j] + bv;
                if (MODE == 0) {
                    v = 0.5f * v * (1.0f + erff(v * 0.70710678118654752f));
                    Hout[((size_t)e * MPAD + row) * N + col] = f2bf(v);
                } else {
                    if (row < kept) {
                        int tok = slot_map[e * CAP + row];
                        Yout[(size_t)tok * D + col] = v;
                    }
                }
            }
        }
    }
}

extern "C" void kernel_launch(void* const* d_in, const int* in_sizes, int n_in,
                              void* d_out, int out_size, void* d_ws, size_t ws_size,
                              hipStream_t stream)
{
    const float* x   = (const float*)d_in[0];
    const float* gw  = (const float*)d_in[1];
    const float* lng = (const float*)d_in[2];
    const float* lnb = (const float*)d_in[3];
    const float* w1  = (const float*)d_in[4];
    const float* b1  = (const float*)d_in[5];
    const float* w2  = (const float*)d_in[6];
    const float* b2  = (const float*)d_in[7];
    float* out = (float*)d_out;

    char* ws = (char*)d_ws;
    unsigned short* wT   = (unsigned short*)ws;                               // 67108864 B (reused for w1T then w2T)
    unsigned short* xbuf = (unsigned short*)(ws + 67108864);                  // 18874368 B
    unsigned short* hbuf = (unsigned short*)(ws + 67108864 + 18874368);       // 75497472 B
    int* eidx     = (int*)(ws + 161480704);
    int* slot_map = eidx + NTOK;
    int* kept     = slot_map + NEXP * CAP;

    router_kernel<<<NTOK / 4, 256, 0, stream>>>(x, gw, eidx);
    scan_kernel<<<1, 1024, 0, stream>>>(eidx, slot_map, kept, out + (size_t)NTOK * D);
    zero_out<<<2048, 256, 0, stream>>>((float4*)out, NTOK * D / 4);
    dispatch_ln<<<dim3(MPAD, NEXP), 256, 0, stream>>>(x, lng, lnb, slot_map, kept, xbuf);

    // GEMM1: h = gelu(xbuf @ w1 + b1)
    transpose_bf16<<<dim3(DFF / 64, D / 64, NEXP), 256, 0, stream>>>(w1, wT, D, DFF);
    gemm_kernel<D, DFF, 0><<<NEXP * (MPAD / 128) * (DFF / 128), 256, 0, stream>>>(
        xbuf, wT, b1, hbuf, nullptr, slot_map, kept);

    // GEMM2: out[token] = h @ w2 + b2 (scatter)
    transpose_bf16<<<dim3(D / 64, DFF / 64, NEXP), 256, 0, stream>>>(w2, wT, DFF, D);
    gemm_kernel<DFF, D, 1><<<NEXP * (MPAD / 128) * (D / 128), 256, 0, stream>>>(
        hbuf, wT, b2, nullptr, out, slot_map, kept);
}